// Round 8
// baseline (314.721 us; speedup 1.0000x reference)
//
#include <hip/hip_runtime.h>
#include <hip/hip_bf16.h>

// Problem constants
#define T_TOK 2048      // B*S
#define DDIM  1024
#define EEXP  8
#define KTOP  2
#define HDIM  2816
#define HSDIM 1536
#define BK    64
#define MT    128       // GEMM m-tile
#define NB_UP 22        // HDIM/128
#define NB_SH 12        // HSDIM/128
#define NB_DN 8         // DDIM/128
#define GRID_UP 1072    // max live: 12*56 + 10*40
#define GRID_DN 448     // 8*56

typedef float f32x4 __attribute__((ext_vector_type(4)));
typedef short bf16x8 __attribute__((ext_vector_type(8)));

__device__ __forceinline__ unsigned short f2bf(float f) {
    __hip_bfloat16 h = __float2bfloat16(f);
    return __builtin_bit_cast(unsigned short, h);
}

// async global->LDS, 16B per lane; LDS dest = wave-uniform base + lane*16
__device__ __forceinline__ void gload16(const void* g, void* l) {
    __builtin_amdgcn_global_load_lds(
        (const __attribute__((address_space(1))) unsigned int*)g,
        (__attribute__((address_space(3))) unsigned int*)l, 16, 0, 0);
}

// Bijective chunked XCD remap over a RUNTIME live count (m204 general form).
__device__ __forceinline__ int xcd_live_map(int i, int n) {
    int q = n >> 3, r = n & 7;
    int xcd = i & 7, loc = i >> 3;
    int cap = q + (xcd < r ? 1 : 0);
    if (loc >= cap) return -1;
    return (xcd < r ? xcd * (q + 1) : r * (q + 1) + (xcd - r) * q) + loc;
}

// ---------------- small routing kernels ----------------

__global__ void init_k(int* counts, int* cursors) {
    if (threadIdx.x < EEXP) { counts[threadIdx.x] = 0; cursors[threadIdx.x] = 0; }
}

__global__ void gate_k(const float* __restrict__ X, const float* __restrict__ GW,
                       int* __restrict__ topi, float* __restrict__ topw,
                       int* __restrict__ counts) {
    int lane = threadIdx.x & 63;
    int t = blockIdx.x * 4 + (threadIdx.x >> 6);
    int e  = lane >> 3;
    int c8 = lane & 7;
    const float* xr = X + (size_t)t * DDIM;
    const float* gr = GW + (size_t)e * DDIM;
    float acc = 0.f;
#pragma unroll 8
    for (int j = 0; j < 32; j++) {
        int d = (c8 + 8 * j) * 4;
        float4 xv = *(const float4*)(xr + d);
        float4 gv = *(const float4*)(gr + d);
        acc += xv.x * gv.x + xv.y * gv.y + xv.z * gv.z + xv.w * gv.w;
    }
    acc += __shfl_xor(acc, 1);
    acc += __shfl_xor(acc, 2);
    acc += __shfl_xor(acc, 4);
    float p[8];
#pragma unroll
    for (int q = 0; q < 8; q++) p[q] = __shfl(acc, q * 8);
    float mx = p[0];
#pragma unroll
    for (int q = 1; q < 8; q++) mx = fmaxf(mx, p[q]);
    float s = 0.f;
#pragma unroll
    for (int q = 0; q < 8; q++) { p[q] = expf(p[q] - mx); s += p[q]; }
    float inv = 1.f / s;
#pragma unroll
    for (int q = 0; q < 8; q++) p[q] *= inv;
    float v1 = -1.f; int i1 = 0;
#pragma unroll
    for (int q = 0; q < 8; q++) { if (p[q] > v1) { v1 = p[q]; i1 = q; } }
    float v2 = -1.f; int i2 = 0;
#pragma unroll
    for (int q = 0; q < 8; q++) { if (q != i1 && p[q] > v2) { v2 = p[q]; i2 = q; } }
    if (lane == 0) {
        topi[2 * t] = i1; topi[2 * t + 1] = i2;
        topw[2 * t] = v1; topw[2 * t + 1] = v2;
        atomicAdd(&counts[i1], 1);
        atomicAdd(&counts[i2], 1);
    }
}

// prefix-sum + device-built tile worklist: (e<<16)|m0 ; routed tiles FIRST,
// then shared-expert (e=8) tiles. wl_n[0]=total items, wl_n[1]=routed items.
__global__ void scan_k(const int* __restrict__ counts, int* __restrict__ offsets,
                       int* __restrict__ wl, int* __restrict__ wl_n) {
    if (threadIdx.x == 0) {
        int s = 0;
        for (int e = 0; e < EEXP; e++) { offsets[e] = s; s += counts[e]; }
        offsets[EEXP] = s;
        int n = 0;
        for (int e = 0; e < EEXP; e++) {
            int Ne = counts[e];
            for (int m0 = 0; m0 < Ne; m0 += MT) wl[n++] = (e << 16) | m0;
        }
        wl_n[1] = n;                       // routed count
        for (int m0 = 0; m0 < T_TOK; m0 += MT) wl[n++] = (EEXP << 16) | m0;
        wl_n[0] = n;                       // total (<= 56)
    }
}

__global__ void build_k(const int* __restrict__ topi, const int* __restrict__ offsets,
                        int* __restrict__ cursors, int* __restrict__ rows_token,
                        int* __restrict__ rowof) {
    int t = blockIdx.x * 256 + threadIdx.x;
    if (t >= T_TOK) return;
    for (int k = 0; k < KTOP; k++) {
        int e = topi[2 * t + k];
        int pos = atomicAdd(&cursors[e], 1);
        int r = offsets[e] + pos;
        rows_token[r] = t;
        rowof[2 * t + k] = r;
    }
}

// ---------------- consolidated pre-pass ----------------
// 128(k) x 64(n) f32->bf16 transpose tile, restructured around global_load_lds:
// stage f32 tile into LDS fire-and-forget (no dest VGPRs -> all loads in flight),
// 16B-chunk XOR swizzle (chunk ^= (row>>2)&7) applied on global SOURCE per lane
// (rows in one instr share base>>2 -> wave-legal) and on the ds_read side.
__device__ __forceinline__ void tcast_tile(const float* __restrict__ S,
                                           unsigned short* __restrict__ Dm,
                                           int Kd, int Nn, int k0, int n0,
                                           float* __restrict__ ld /*[128*64]*/) {
    int tid = threadIdx.x, lane = tid & 63, w = tid >> 6;
#pragma unroll
    for (int j = 0; j < 8; j++) {
        int base = j * 16 + w * 4;                 // 4-aligned row group
        int r = base + (lane >> 4);
        int c = (lane & 15) ^ ((base >> 2) & 7);   // inverse-swizzled source chunk
        gload16(S + (size_t)(k0 + r) * Nn + n0 + c * 4, ld + base * 64);
    }
    __syncthreads();
    // read b128 (swizzled), 4x8 register transpose, cvt, coalesced 16B stores
    int nq = tid >> 4;            // n-quad 0..15
    int kc = (tid & 15) * 8;      // k base
    f32x4 blk[8];
#pragma unroll
    for (int i = 0; i < 8; i++) {
        int k = kc + i;
        blk[i] = *(const f32x4*)(ld + k * 64 + ((nq ^ ((k >> 2) & 7)) << 2));
    }
#pragma unroll
    for (int v = 0; v < 4; v++) {
        unsigned short o[8];
#pragma unroll
        for (int i = 0; i < 8; i++) o[i] = f2bf(blk[i][v]);
        *(uint4*)(Dm + (size_t)(n0 + nq * 4 + v) * Kd + k0 + kc) = *(const uint4*)o;
    }
}

// job table:
//  [0,1024)       xcast: X f32 -> Xb bf16
//  [1024,3840)    w1  -> W1t   (z,kb,nb)
//  [3840,6656)    w3  -> W3t
//  [6656,6848)    sw1 -> sw1t
//  [6848,7040)    sw3 -> sw3t
//  [7040,7232)    sw2 -> sw2t
//  [7232,10048)   w2  -> W2t   (only when ws_size allows separate W2t region)
#define PREP_GRID     7232
#define PREP_GRID_W2 10048

__global__ __launch_bounds__(256) void prep_k(
    const float* __restrict__ x,
    const float* __restrict__ w1, const float* __restrict__ w3,
    const float* __restrict__ sw1, const float* __restrict__ sw3,
    const float* __restrict__ sw2, const float* __restrict__ w2,
    unsigned short* __restrict__ Xb,
    unsigned short* __restrict__ W1t, unsigned short* __restrict__ W3t,
    unsigned short* __restrict__ sw1t, unsigned short* __restrict__ sw3t,
    unsigned short* __restrict__ sw2t, unsigned short* __restrict__ W2t)
{
    __shared__ __align__(16) float ld[128 * 64];
    int b = blockIdx.x;
    if (b < 1024) {
        int i = b * 2048 + threadIdx.x * 8;
        float4 a = *(const float4*)(x + i);
        float4 c = *(const float4*)(x + i + 4);
        unsigned short o[8] = { f2bf(a.x), f2bf(a.y), f2bf(a.z), f2bf(a.w),
                                f2bf(c.x), f2bf(c.y), f2bf(c.z), f2bf(c.w) };
        *(uint4*)(Xb + i) = *(const uint4*)o;
        return;
    }
    const float* S; unsigned short* D; int Kd, Nn, k0, n0;
    if (b < 3840) {
        int idx = b - 1024, z = idx / 352, r = idx % 352;
        Kd = DDIM; Nn = HDIM;
        S = w1 + (size_t)z * DDIM * HDIM; D = W1t + (size_t)z * DDIM * HDIM;
        k0 = (r / 44) * 128; n0 = (r % 44) * 64;
    } else if (b < 6656) {
        int idx = b - 3840, z = idx / 352, r = idx % 352;
        Kd = DDIM; Nn = HDIM;
        S = w3 + (size_t)z * DDIM * HDIM; D = W3t + (size_t)z * DDIM * HDIM;
        k0 = (r / 44) * 128; n0 = (r % 44) * 64;
    } else if (b < 6848) {
        int idx = b - 6656;
        Kd = DDIM; Nn = HSDIM; S = sw1; D = sw1t;
        k0 = (idx / 24) * 128; n0 = (idx % 24) * 64;
    } else if (b < 7040) {
        int idx = b - 6848;
        Kd = DDIM; Nn = HSDIM; S = sw3; D = sw3t;
        k0 = (idx / 24) * 128; n0 = (idx % 24) * 64;
    } else if (b < 7232) {
        int idx = b - 7040;
        Kd = HSDIM; Nn = DDIM; S = sw2; D = sw2t;
        k0 = (idx / 16) * 128; n0 = (idx % 16) * 64;
    } else {
        int idx = b - 7232, z = idx / 352, r = idx % 352;
        Kd = HDIM; Nn = DDIM;
        S = w2 + (size_t)z * HDIM * DDIM; D = W2t + (size_t)z * DDIM * HDIM;
        k0 = (r / 16) * 128; n0 = (r % 16) * 64;
    }
    tcast_tile(S, D, Kd, Nn, k0, n0, ld);
}

// W [z][K][N] f32 -> Wt [z][N][K] bf16 (fallback W2 path, aliased region)
__global__ __launch_bounds__(256) void tcast_k(const float* __restrict__ S,
                                               unsigned short* __restrict__ Dm,
                                               int Kd, int Nn) {
    __shared__ __align__(16) float ld[128 * 64];
    size_t zoff = (size_t)blockIdx.z * Kd * Nn;
    tcast_tile(S + zoff, Dm + zoff, Kd, Nn, blockIdx.y * 128, blockIdx.x * 64, ld);
}

// ---------------- fused up-projection: H = silu(X@W1) * (X@W3) ----------------
// tile 128(M) x 128(N), BK=64, 4 waves 2x2, per-wave 64x64 dual-accumulated.
// Live-compacted n-major logical space: nb<12 -> all items; nb>=12 -> routed only.
__global__ __launch_bounds__(256, 2) void fused_up(
    const unsigned short* __restrict__ Xb,
    const int* __restrict__ rows_token,
    const int* __restrict__ offsets,
    const unsigned short* __restrict__ W1t,   // [8][H][D] bf16
    const unsigned short* __restrict__ W3t,
    const unsigned short* __restrict__ sw1t,  // [HS][D]
    const unsigned short* __restrict__ sw3t,
    unsigned short* __restrict__ Hg,          // [4096][H]
    unsigned short* __restrict__ Hs,          // [2048][HS]
    const int* __restrict__ wl, const int* __restrict__ wl_n)
{
    int n_all = wl_n[0], n_r = wl_n[1];
    int live = NB_SH * n_all + (NB_UP - NB_SH) * n_r;
    int L = xcd_live_map(blockIdx.x, live);
    if (L < 0 || L >= live) return;
    int nb, it;
    if (L < NB_SH * n_all) { nb = L / n_all; it = L % n_all; }
    else { int L2 = L - NB_SH * n_all; nb = NB_SH + L2 / n_r; it = L2 % n_r; }
    int pk = wl[it];
    int z = pk >> 16, m0 = pk & 0xffff;
    bool sh = (z == EEXP);
    int roff, Ne, Nn;
    const unsigned short *w1, *w3;
    unsigned short* Ho;
    if (sh) { roff = 0; Ne = T_TOK; Nn = HSDIM; w1 = sw1t; w3 = sw3t; Ho = Hs; }
    else {
        roff = offsets[z]; Ne = offsets[z + 1] - roff; Nn = HDIM;
        w1 = W1t + (size_t)z * HDIM * DDIM;
        w3 = W3t + (size_t)z * HDIM * DDIM;
        Ho = Hg;
    }
    int n0 = nb * 128;
    if (n0 >= Nn) return;   // safety net (should not trigger)

    __shared__ __align__(16) unsigned short As [128 * 64];
    __shared__ __align__(16) unsigned short B1s[128 * 64];
    __shared__ __align__(16) unsigned short B3s[128 * 64];

    int tid = threadIdx.x, lane = tid & 63, wid = tid >> 6;
    int wr = wid >> 1, wc = wid & 1;          // per-wave 64 rows x 64 cols
    int sc = ((lane & 7) ^ (lane >> 3)) * 8;  // inverse-swizzled source chunk

    const unsigned short* pA[4];
    const unsigned short *pB1[4], *pB3[4];
#pragma unroll
    for (int j = 0; j < 4; j++) {
        int lr = (wid * 4 + j) * 8 + (lane >> 3);
        int gr = m0 + lr; if (gr >= Ne) gr = Ne - 1;
        int tok = sh ? gr : rows_token[roff + gr];
        pA[j]  = Xb + (size_t)tok * DDIM + sc;
        pB1[j] = w1 + (size_t)(n0 + lr) * DDIM + sc;
        pB3[j] = w3 + (size_t)(n0 + lr) * DDIM + sc;
    }

    const f32x4 fz = {0.f, 0.f, 0.f, 0.f};
    f32x4 acc1[4][4], acc3[4][4];
#pragma unroll
    for (int mi = 0; mi < 4; mi++)
#pragma unroll
        for (int nj = 0; nj < 4; nj++) { acc1[mi][nj] = fz; acc3[mi][nj] = fz; }

#pragma unroll 1
    for (int ks = 0; ks < DDIM / BK; ks++) {
        __syncthreads();
#pragma unroll
        for (int j = 0; j < 4; j++) gload16(pA[j],  As  + (wid * 4 + j) * 512);
#pragma unroll
        for (int j = 0; j < 4; j++) gload16(pB1[j], B1s + (wid * 4 + j) * 512);
#pragma unroll
        for (int j = 0; j < 4; j++) gload16(pB3[j], B3s + (wid * 4 + j) * 512);
#pragma unroll
        for (int j = 0; j < 4; j++) { pA[j] += BK; pB1[j] += BK; pB3[j] += BK; }
        __syncthreads();
        int r = lane & 15, h = lane >> 4, sw = (lane & 7) << 4;
#pragma unroll
        for (int kk = 0; kk < 2; kk++) {
            int cb = (kk * 64 + h * 16) ^ sw;
            bf16x8 a[4], b1[4], b3[4];
#pragma unroll
            for (int mi = 0; mi < 4; mi++)
                a[mi] = *(const bf16x8*)((const char*)As + (wr * 64 + mi * 16 + r) * 128 + cb);
#pragma unroll
            for (int nj = 0; nj < 4; nj++) {
                b1[nj] = *(const bf16x8*)((const char*)B1s + (wc * 64 + nj * 16 + r) * 128 + cb);
                b3[nj] = *(const bf16x8*)((const char*)B3s + (wc * 64 + nj * 16 + r) * 128 + cb);
            }
#pragma unroll
            for (int mi = 0; mi < 4; mi++)
#pragma unroll
                for (int nj = 0; nj < 4; nj++) {
                    acc1[mi][nj] = __builtin_amdgcn_mfma_f32_16x16x32_bf16(a[mi], b1[nj], acc1[mi][nj], 0, 0, 0);
                    acc3[mi][nj] = __builtin_amdgcn_mfma_f32_16x16x32_bf16(a[mi], b3[nj], acc3[mi][nj], 0, 0, 0);
                }
        }
    }
    int r = lane & 15, h = lane >> 4;
#pragma unroll
    for (int mi = 0; mi < 4; mi++) {
#pragma unroll
        for (int nj = 0; nj < 4; nj++) {
            int col = n0 + wc * 64 + nj * 16 + r;
#pragma unroll
            for (int j = 0; j < 4; j++) {
                int row = wr * 64 + mi * 16 + h * 4 + j;
                if (m0 + row < Ne) {
                    float aa = acc1[mi][nj][j], bb = acc3[mi][nj][j];
                    float hv = (aa / (1.f + expf(-aa))) * bb;
                    Ho[(size_t)(roff + m0 + row) * Nn + col] = f2bf(hv);
                }
            }
        }
    }
}

// ---------------- down-projection: Y = H @ W2 ----------------
// tile 128(M) x 128(N), BK=64; live = NB_DN * n_all (all items valid for all nb).
__global__ __launch_bounds__(256) void gemm2(
    const unsigned short* __restrict__ Hg,
    const unsigned short* __restrict__ Hs,
    const unsigned short* __restrict__ W2t,   // [8][D][H] bf16
    const unsigned short* __restrict__ sw2t,  // [D][HS]
    const int* __restrict__ offsets,
    float* __restrict__ Yg,
    float* __restrict__ out,
    const int* __restrict__ wl, const int* __restrict__ wl_n)
{
    int n_all = wl_n[0];
    int live = NB_DN * n_all;
    int L = xcd_live_map(blockIdx.x, live);
    if (L < 0 || L >= live) return;
    int nb = L / n_all, it = L % n_all;
    int pk = wl[it];
    int z = pk >> 16, m0 = pk & 0xffff;
    bool sh = (z == EEXP);
    int roff, Ne, Kd;
    const unsigned short *Ab, *Bb;
    float* Yo;
    if (sh) { roff = 0; Ne = T_TOK; Kd = HSDIM; Ab = Hs; Bb = sw2t; Yo = out; }
    else {
        roff = offsets[z]; Ne = offsets[z + 1] - roff; Kd = HDIM;
        Ab = Hg + (size_t)roff * HDIM;
        Bb = W2t + (size_t)z * DDIM * HDIM;
        Yo = Yg + (size_t)roff * DDIM;
    }
    int n0 = nb * 128;

    __shared__ __align__(16) unsigned short As[128 * 64];
    __shared__ __align__(16) unsigned short Bs[128 * 64];

    int tid = threadIdx.x, lane = tid & 63, wid = tid >> 6;
    int wr = wid >> 1, wc = wid & 1;
    int sc = ((lane & 7) ^ (lane >> 3)) * 8;

    const unsigned short* pA[4];
    const unsigned short* pB[4];
#pragma unroll
    for (int j = 0; j < 4; j++) {
        int lr = (wid * 4 + j) * 8 + (lane >> 3);
        int gr = m0 + lr; if (gr >= Ne) gr = Ne - 1;
        pA[j] = Ab + (size_t)gr * Kd + sc;
        pB[j] = Bb + (size_t)(n0 + lr) * Kd + sc;
    }

    const f32x4 fz = {0.f, 0.f, 0.f, 0.f};
    f32x4 acc[4][4];
#pragma unroll
    for (int mi = 0; mi < 4; mi++)
#pragma unroll
        for (int nj = 0; nj < 4; nj++) acc[mi][nj] = fz;

    int nks = Kd / BK;
#pragma unroll 1
    for (int ks = 0; ks < nks; ks++) {
        __syncthreads();
#pragma unroll
        for (int j = 0; j < 4; j++) gload16(pA[j], As + (wid * 4 + j) * 512);
#pragma unroll
        for (int j = 0; j < 4; j++) gload16(pB[j], Bs + (wid * 4 + j) * 512);
#pragma unroll
        for (int j = 0; j < 4; j++) { pA[j] += BK; pB[j] += BK; }
        __syncthreads();
        int r = lane & 15, h = lane >> 4, sw = (lane & 7) << 4;
#pragma unroll
        for (int kk = 0; kk < 2; kk++) {
            int cb = (kk * 64 + h * 16) ^ sw;
            bf16x8 a[4], b[4];
#pragma unroll
            for (int mi = 0; mi < 4; mi++)
                a[mi] = *(const bf16x8*)((const char*)As + (wr * 64 + mi * 16 + r) * 128 + cb);
#pragma unroll
            for (int nj = 0; nj < 4; nj++)
                b[nj] = *(const bf16x8*)((const char*)Bs + (wc * 64 + nj * 16 + r) * 128 + cb);
#pragma unroll
            for (int mi = 0; mi < 4; mi++)
#pragma unroll
                for (int nj = 0; nj < 4; nj++)
                    acc[mi][nj] = __builtin_amdgcn_mfma_f32_16x16x32_bf16(a[mi], b[nj], acc[mi][nj], 0, 0, 0);
        }
    }
    int r = lane & 15, h = lane >> 4;
#pragma unroll
    for (int mi = 0; mi < 4; mi++) {
#pragma unroll
        for (int nj = 0; nj < 4; nj++) {
            int col = n0 + wc * 64 + nj * 16 + r;
#pragma unroll
            for (int j = 0; j < 4; j++) {
                int row = wr * 64 + mi * 16 + h * 4 + j;
                if (m0 + row < Ne)
                    Yo[(size_t)(m0 + row) * DDIM + col] = acc[mi][nj][j];
            }
        }
    }
}

// ---------------- final combine ----------------
__global__ void combine_k(float* __restrict__ out, const float* __restrict__ Yg,
                          const int* __restrict__ rowof, const float* __restrict__ topw) {
    int idx = blockIdx.x * 256 + threadIdx.x;
    int t = idx >> 8;
    int dq = (idx & 255) << 2;
    int r0 = rowof[2 * t], r1 = rowof[2 * t + 1];
    float g0 = topw[2 * t], g1 = topw[2 * t + 1];
    float* op = out + (size_t)t * DDIM + dq;
    float4 o = *(float4*)op;
    float4 a = *(const float4*)(Yg + (size_t)r0 * DDIM + dq);
    float4 b = *(const float4*)(Yg + (size_t)r1 * DDIM + dq);
    o.x += g0 * a.x + g1 * b.x;
    o.y += g0 * a.y + g1 * b.y;
    o.z += g0 * a.z + g1 * b.z;
    o.w += g0 * a.w + g1 * b.w;
    *(float4*)op = o;
}

// ---------------- launch ----------------
extern "C" void kernel_launch(void* const* d_in, const int* in_sizes, int n_in,
                              void* d_out, int out_size, void* d_ws, size_t ws_size,
                              hipStream_t stream) {
    const float* x   = (const float*)d_in[0];
    const float* gw  = (const float*)d_in[1];
    const float* w1  = (const float*)d_in[2];
    const float* w3  = (const float*)d_in[3];
    const float* w2  = (const float*)d_in[4];
    const float* sw1 = (const float*)d_in[5];
    const float* sw3 = (const float*)d_in[6];
    const float* sw2 = (const float*)d_in[7];
    float* out = (float*)d_out;
    char* ws = (char*)d_ws;

    const size_t MB = 1048576;
    int*   counts     = (int*)(ws);
    int*   offsets    = (int*)(ws + 64);
    int*   cursors    = (int*)(ws + 128);
    int*   wl_n       = (int*)(ws + 192);     // [0]=total, [1]=routed
    int*   wl         = (int*)(ws + 256);
    int*   topi       = (int*)(ws + 512);
    float* topw       = (float*)(ws + 16896);
    int*   rows_token = (int*)(ws + 33280);
    int*   rowof      = (int*)(ws + 49664);
    unsigned short* Xb   = (unsigned short*)(ws + 1 * MB);    // 4 MB
    unsigned short* sw1t = (unsigned short*)(ws + 6 * MB);    // 3 MB
    unsigned short* sw3t = (unsigned short*)(ws + 9 * MB);    // 3 MB
    unsigned short* sw2t = (unsigned short*)(ws + 12 * MB);   // 3 MB
    unsigned short* Hg   = (unsigned short*)(ws + 16 * MB);   // 22 MB
    float*          Yg   = (float*)(ws + 40 * MB);            // 16 MB
    unsigned short* Hs   = (unsigned short*)(ws + 56 * MB);   // 6 MB
    unsigned short* W1t  = (unsigned short*)(ws + 64 * MB);   // 44 MB
    unsigned short* W3t  = (unsigned short*)(ws + 108 * MB);  // 44 MB (ends 152 MB)

    // W2t: separate region if workspace allows (152+44=196 MB), else alias W1t
    // (converted after fused_up consumes W1t). ws_size is call-invariant ->
    // deterministic kernel sequence.
    bool sepW2 = (ws_size >= 196 * MB);
    unsigned short* W2t = sepW2 ? (unsigned short*)(ws + 152 * MB) : W1t;

    // routing
    init_k<<<1, 64, 0, stream>>>(counts, cursors);
    gate_k<<<T_TOK / 4, 256, 0, stream>>>(x, gw, topi, topw, counts);
    scan_k<<<1, 64, 0, stream>>>(counts, offsets, wl, wl_n);
    build_k<<<T_TOK / 256, 256, 0, stream>>>(topi, offsets, cursors, rows_token, rowof);

    // consolidated pre-pass: xcast + all transposes (incl. w2 when sepW2)
    prep_k<<<sepW2 ? PREP_GRID_W2 : PREP_GRID, 256, 0, stream>>>(
        x, w1, w3, sw1, sw3, sw2, w2,
        Xb, W1t, W3t, sw1t, sw3t, sw2t, W2t);

    // up-projection (live-compacted n-major grid)
    fused_up<<<GRID_UP, 256, 0, stream>>>(
        Xb, rows_token, offsets, W1t, W3t, sw1t, sw3t, Hg, Hs, wl, wl_n);

    // fallback W2 transpose into aliased region (after fused_up drained W1t)
    if (!sepW2)
        tcast_k<<<dim3(DDIM / 64, HDIM / 128, EEXP), 256, 0, stream>>>(w2, W2t, HDIM, DDIM);

    // down-projection (routed -> Yg, shared -> out direct)
    gemm2<<<GRID_DN, 256, 0, stream>>>(
        Hg, Hs, W2t, sw2t, offsets, Yg, out, wl, wl_n);

    // out = shared + g0*y0 + g1*y1
    combine_k<<<(T_TOK * DDIM / 4) / 256, 256, 0, stream>>>(out, Yg, rowof, topw);
}

// Round 9
// 296.993 us; speedup vs baseline: 1.0597x; 1.0597x over previous
//
#include <hip/hip_runtime.h>
#include <hip/hip_bf16.h>

// Problem constants
#define T_TOK 2048      // B*S
#define DDIM  1024
#define EEXP  8
#define KTOP  2
#define HDIM  2816
#define HSDIM 1536
#define BK    64
#define MT    128       // GEMM m-tile
#define NB_UP 22        // HDIM/128
#define NB_SH 12        // HSDIM/128
#define NB_DN 8         // DDIM/128
#define GRID_UP 1072    // max live: 12*56 + 10*40
#define GRID_DN 448     // 8*56

typedef float f32x4 __attribute__((ext_vector_type(4)));
typedef short bf16x8 __attribute__((ext_vector_type(8)));

__device__ __forceinline__ unsigned short f2bf(float f) {
    __hip_bfloat16 h = __float2bfloat16(f);
    return __builtin_bit_cast(unsigned short, h);
}

// async global->LDS, 16B per lane; LDS dest = wave-uniform base + lane*16
__device__ __forceinline__ void gload16(const void* g, void* l) {
    __builtin_amdgcn_global_load_lds(
        (const __attribute__((address_space(1))) unsigned int*)g,
        (__attribute__((address_space(3))) unsigned int*)l, 16, 0, 0);
}

// Bijective chunked XCD remap over a RUNTIME live count (m204 general form).
__device__ __forceinline__ int xcd_live_map(int i, int n) {
    int q = n >> 3, r = n & 7;
    int xcd = i & 7, loc = i >> 3;
    int cap = q + (xcd < r ? 1 : 0);
    if (loc >= cap) return -1;
    return (xcd < r ? xcd * (q + 1) : r * (q + 1) + (xcd - r) * q) + loc;
}

// ---------------- small routing kernels ----------------

__global__ void init_k(int* counts, int* cursors) {
    if (threadIdx.x < EEXP) { counts[threadIdx.x] = 0; cursors[threadIdx.x] = 0; }
}

__global__ void gate_k(const float* __restrict__ X, const float* __restrict__ GW,
                       int* __restrict__ topi, float* __restrict__ topw,
                       int* __restrict__ counts) {
    int lane = threadIdx.x & 63;
    int t = blockIdx.x * 4 + (threadIdx.x >> 6);
    int e  = lane >> 3;
    int c8 = lane & 7;
    const float* xr = X + (size_t)t * DDIM;
    const float* gr = GW + (size_t)e * DDIM;
    float acc = 0.f;
#pragma unroll 8
    for (int j = 0; j < 32; j++) {
        int d = (c8 + 8 * j) * 4;
        float4 xv = *(const float4*)(xr + d);
        float4 gv = *(const float4*)(gr + d);
        acc += xv.x * gv.x + xv.y * gv.y + xv.z * gv.z + xv.w * gv.w;
    }
    acc += __shfl_xor(acc, 1);
    acc += __shfl_xor(acc, 2);
    acc += __shfl_xor(acc, 4);
    float p[8];
#pragma unroll
    for (int q = 0; q < 8; q++) p[q] = __shfl(acc, q * 8);
    float mx = p[0];
#pragma unroll
    for (int q = 1; q < 8; q++) mx = fmaxf(mx, p[q]);
    float s = 0.f;
#pragma unroll
    for (int q = 0; q < 8; q++) { p[q] = expf(p[q] - mx); s += p[q]; }
    float inv = 1.f / s;
#pragma unroll
    for (int q = 0; q < 8; q++) p[q] *= inv;
    float v1 = -1.f; int i1 = 0;
#pragma unroll
    for (int q = 0; q < 8; q++) { if (p[q] > v1) { v1 = p[q]; i1 = q; } }
    float v2 = -1.f; int i2 = 0;
#pragma unroll
    for (int q = 0; q < 8; q++) { if (q != i1 && p[q] > v2) { v2 = p[q]; i2 = q; } }
    if (lane == 0) {
        topi[2 * t] = i1; topi[2 * t + 1] = i2;
        topw[2 * t] = v1; topw[2 * t + 1] = v2;
        atomicAdd(&counts[i1], 1);
        atomicAdd(&counts[i2], 1);
    }
}

// prefix-sum + device-built tile worklist: (e<<16)|m0 ; routed tiles FIRST,
// then shared-expert (e=8) tiles. wl_n[0]=total items, wl_n[1]=routed items.
__global__ void scan_k(const int* __restrict__ counts, int* __restrict__ offsets,
                       int* __restrict__ wl, int* __restrict__ wl_n) {
    if (threadIdx.x == 0) {
        int s = 0;
        for (int e = 0; e < EEXP; e++) { offsets[e] = s; s += counts[e]; }
        offsets[EEXP] = s;
        int n = 0;
        for (int e = 0; e < EEXP; e++) {
            int Ne = counts[e];
            for (int m0 = 0; m0 < Ne; m0 += MT) wl[n++] = (e << 16) | m0;
        }
        wl_n[1] = n;                       // routed count
        for (int m0 = 0; m0 < T_TOK; m0 += MT) wl[n++] = (EEXP << 16) | m0;
        wl_n[0] = n;                       // total (<= 56)
    }
}

__global__ void build_k(const int* __restrict__ topi, const int* __restrict__ offsets,
                        int* __restrict__ cursors, int* __restrict__ rows_token,
                        int* __restrict__ rowof) {
    int t = blockIdx.x * 256 + threadIdx.x;
    if (t >= T_TOK) return;
    for (int k = 0; k < KTOP; k++) {
        int e = topi[2 * t + k];
        int pos = atomicAdd(&cursors[e], 1);
        int r = offsets[e] + pos;
        rows_token[r] = t;
        rowof[2 * t + k] = r;
    }
}

// ---------------- pre-pass: gload_lds-based cast & transpose ----------------
// 128(k) x 64(n) f32->bf16 transpose tile: stage f32 tile into LDS via
// global_load_lds (fire-and-forget, no dest VGPRs -> all 8 loads/thread in
// flight), 16B-chunk XOR swizzle applied on global SOURCE per lane and on the
// ds_read side (rule #21). Verified R8: 3.8 TB/s effective vs 3.4 for VGPR path.
__device__ __forceinline__ void tcast_tile(const float* __restrict__ S,
                                           unsigned short* __restrict__ Dm,
                                           int Kd, int Nn, int k0, int n0,
                                           float* __restrict__ ld /*[128*64]*/) {
    int tid = threadIdx.x, lane = tid & 63, w = tid >> 6;
#pragma unroll
    for (int j = 0; j < 8; j++) {
        int base = j * 16 + w * 4;                 // 4-aligned row group
        int r = base + (lane >> 4);
        int c = (lane & 15) ^ ((base >> 2) & 7);   // inverse-swizzled source chunk
        gload16(S + (size_t)(k0 + r) * Nn + n0 + c * 4, ld + base * 64);
    }
    __syncthreads();
    // read b128 (swizzled), 4x8 register transpose, cvt, coalesced 16B stores
    int nq = tid >> 4;            // n-quad 0..15
    int kc = (tid & 15) * 8;      // k base
    f32x4 blk[8];
#pragma unroll
    for (int i = 0; i < 8; i++) {
        int k = kc + i;
        blk[i] = *(const f32x4*)(ld + k * 64 + ((nq ^ ((k >> 2) & 7)) << 2));
    }
#pragma unroll
    for (int v = 0; v < 4; v++) {
        unsigned short o[8];
#pragma unroll
        for (int i = 0; i < 8; i++) o[i] = f2bf(blk[i][v]);
        *(uint4*)(Dm + (size_t)(n0 + nq * 4 + v) * Kd + k0 + kc) = *(const uint4*)o;
    }
}

// job table (W2 deliberately NOT here: its transpose runs AFTER fused_up so
// W1t/W3t stay L3-warm for fused_up and W2t stays warm for gemm2 — R8 lesson):
//  [0,1024)       xcast: X f32 -> Xb bf16
//  [1024,3840)    w1  -> W1t   (z,kb,nb)
//  [3840,6656)    w3  -> W3t
//  [6656,6848)    sw1 -> sw1t
//  [6848,7040)    sw3 -> sw3t
//  [7040,7232)    sw2 -> sw2t
#define PREP_GRID 7232

__global__ __launch_bounds__(256) void prep_k(
    const float* __restrict__ x,
    const float* __restrict__ w1, const float* __restrict__ w3,
    const float* __restrict__ sw1, const float* __restrict__ sw3,
    const float* __restrict__ sw2,
    unsigned short* __restrict__ Xb,
    unsigned short* __restrict__ W1t, unsigned short* __restrict__ W3t,
    unsigned short* __restrict__ sw1t, unsigned short* __restrict__ sw3t,
    unsigned short* __restrict__ sw2t)
{
    __shared__ __align__(16) float ld[128 * 64];
    int b = blockIdx.x;
    if (b < 1024) {
        int i = b * 2048 + threadIdx.x * 8;
        float4 a = *(const float4*)(x + i);
        float4 c = *(const float4*)(x + i + 4);
        unsigned short o[8] = { f2bf(a.x), f2bf(a.y), f2bf(a.z), f2bf(a.w),
                                f2bf(c.x), f2bf(c.y), f2bf(c.z), f2bf(c.w) };
        *(uint4*)(Xb + i) = *(const uint4*)o;
        return;
    }
    const float* S; unsigned short* D; int Kd, Nn, k0, n0;
    if (b < 3840) {
        int idx = b - 1024, z = idx / 352, r = idx % 352;
        Kd = DDIM; Nn = HDIM;
        S = w1 + (size_t)z * DDIM * HDIM; D = W1t + (size_t)z * DDIM * HDIM;
        k0 = (r / 44) * 128; n0 = (r % 44) * 64;
    } else if (b < 6656) {
        int idx = b - 3840, z = idx / 352, r = idx % 352;
        Kd = DDIM; Nn = HDIM;
        S = w3 + (size_t)z * DDIM * HDIM; D = W3t + (size_t)z * DDIM * HDIM;
        k0 = (r / 44) * 128; n0 = (r % 44) * 64;
    } else if (b < 6848) {
        int idx = b - 6656;
        Kd = DDIM; Nn = HSDIM; S = sw1; D = sw1t;
        k0 = (idx / 24) * 128; n0 = (idx % 24) * 64;
    } else if (b < 7040) {
        int idx = b - 6848;
        Kd = DDIM; Nn = HSDIM; S = sw3; D = sw3t;
        k0 = (idx / 24) * 128; n0 = (idx % 24) * 64;
    } else {
        int idx = b - 7040;
        Kd = HSDIM; Nn = DDIM; S = sw2; D = sw2t;
        k0 = (idx / 16) * 128; n0 = (idx % 16) * 64;
    }
    tcast_tile(S, D, Kd, Nn, k0, n0, ld);
}

// W [z][K][N] f32 -> Wt [z][N][K] bf16 (W2 path, aliased region, runs after
// fused_up has drained W1t)
__global__ __launch_bounds__(256) void tcast_k(const float* __restrict__ S,
                                               unsigned short* __restrict__ Dm,
                                               int Kd, int Nn) {
    __shared__ __align__(16) float ld[128 * 64];
    size_t zoff = (size_t)blockIdx.z * Kd * Nn;
    tcast_tile(S + zoff, Dm + zoff, Kd, Nn, blockIdx.y * 128, blockIdx.x * 64, ld);
}

// ---------------- fused up-projection: H = silu(X@W1) * (X@W3) ----------------
// tile 128(M) x 128(N), BK=64, 4 waves 2x2, per-wave 64x64 dual-accumulated.
// Live-compacted n-major logical space: nb<12 -> all items; nb>=12 -> routed only.
__global__ __launch_bounds__(256, 2) void fused_up(
    const unsigned short* __restrict__ Xb,
    const int* __restrict__ rows_token,
    const int* __restrict__ offsets,
    const unsigned short* __restrict__ W1t,   // [8][H][D] bf16
    const unsigned short* __restrict__ W3t,
    const unsigned short* __restrict__ sw1t,  // [HS][D]
    const unsigned short* __restrict__ sw3t,
    unsigned short* __restrict__ Hg,          // [4096][H]
    unsigned short* __restrict__ Hs,          // [2048][HS]
    const int* __restrict__ wl, const int* __restrict__ wl_n)
{
    int n_all = wl_n[0], n_r = wl_n[1];
    int live = NB_SH * n_all + (NB_UP - NB_SH) * n_r;
    int L = xcd_live_map(blockIdx.x, live);
    if (L < 0 || L >= live) return;
    int nb, it;
    if (L < NB_SH * n_all) { nb = L / n_all; it = L % n_all; }
    else { int L2 = L - NB_SH * n_all; nb = NB_SH + L2 / n_r; it = L2 % n_r; }
    int pk = wl[it];
    int z = pk >> 16, m0 = pk & 0xffff;
    bool sh = (z == EEXP);
    int roff, Ne, Nn;
    const unsigned short *w1, *w3;
    unsigned short* Ho;
    if (sh) { roff = 0; Ne = T_TOK; Nn = HSDIM; w1 = sw1t; w3 = sw3t; Ho = Hs; }
    else {
        roff = offsets[z]; Ne = offsets[z + 1] - roff; Nn = HDIM;
        w1 = W1t + (size_t)z * HDIM * DDIM;
        w3 = W3t + (size_t)z * HDIM * DDIM;
        Ho = Hg;
    }
    int n0 = nb * 128;
    if (n0 >= Nn) return;   // safety net (should not trigger)

    __shared__ __align__(16) unsigned short As [128 * 64];
    __shared__ __align__(16) unsigned short B1s[128 * 64];
    __shared__ __align__(16) unsigned short B3s[128 * 64];

    int tid = threadIdx.x, lane = tid & 63, wid = tid >> 6;
    int wr = wid >> 1, wc = wid & 1;          // per-wave 64 rows x 64 cols
    int sc = ((lane & 7) ^ (lane >> 3)) * 8;  // inverse-swizzled source chunk

    const unsigned short* pA[4];
    const unsigned short *pB1[4], *pB3[4];
#pragma unroll
    for (int j = 0; j < 4; j++) {
        int lr = (wid * 4 + j) * 8 + (lane >> 3);
        int gr = m0 + lr; if (gr >= Ne) gr = Ne - 1;
        int tok = sh ? gr : rows_token[roff + gr];
        pA[j]  = Xb + (size_t)tok * DDIM + sc;
        pB1[j] = w1 + (size_t)(n0 + lr) * DDIM + sc;
        pB3[j] = w3 + (size_t)(n0 + lr) * DDIM + sc;
    }

    const f32x4 fz = {0.f, 0.f, 0.f, 0.f};
    f32x4 acc1[4][4], acc3[4][4];
#pragma unroll
    for (int mi = 0; mi < 4; mi++)
#pragma unroll
        for (int nj = 0; nj < 4; nj++) { acc1[mi][nj] = fz; acc3[mi][nj] = fz; }

#pragma unroll 1
    for (int ks = 0; ks < DDIM / BK; ks++) {
        __syncthreads();
#pragma unroll
        for (int j = 0; j < 4; j++) gload16(pA[j],  As  + (wid * 4 + j) * 512);
#pragma unroll
        for (int j = 0; j < 4; j++) gload16(pB1[j], B1s + (wid * 4 + j) * 512);
#pragma unroll
        for (int j = 0; j < 4; j++) gload16(pB3[j], B3s + (wid * 4 + j) * 512);
#pragma unroll
        for (int j = 0; j < 4; j++) { pA[j] += BK; pB1[j] += BK; pB3[j] += BK; }
        __syncthreads();
        int r = lane & 15, h = lane >> 4, sw = (lane & 7) << 4;
#pragma unroll
        for (int kk = 0; kk < 2; kk++) {
            int cb = (kk * 64 + h * 16) ^ sw;
            bf16x8 a[4], b1[4], b3[4];
#pragma unroll
            for (int mi = 0; mi < 4; mi++)
                a[mi] = *(const bf16x8*)((const char*)As + (wr * 64 + mi * 16 + r) * 128 + cb);
#pragma unroll
            for (int nj = 0; nj < 4; nj++) {
                b1[nj] = *(const bf16x8*)((const char*)B1s + (wc * 64 + nj * 16 + r) * 128 + cb);
                b3[nj] = *(const bf16x8*)((const char*)B3s + (wc * 64 + nj * 16 + r) * 128 + cb);
            }
#pragma unroll
            for (int mi = 0; mi < 4; mi++)
#pragma unroll
                for (int nj = 0; nj < 4; nj++) {
                    acc1[mi][nj] = __builtin_amdgcn_mfma_f32_16x16x32_bf16(a[mi], b1[nj], acc1[mi][nj], 0, 0, 0);
                    acc3[mi][nj] = __builtin_amdgcn_mfma_f32_16x16x32_bf16(a[mi], b3[nj], acc3[mi][nj], 0, 0, 0);
                }
        }
    }
    int r = lane & 15, h = lane >> 4;
#pragma unroll
    for (int mi = 0; mi < 4; mi++) {
#pragma unroll
        for (int nj = 0; nj < 4; nj++) {
            int col = n0 + wc * 64 + nj * 16 + r;
#pragma unroll
            for (int j = 0; j < 4; j++) {
                int row = wr * 64 + mi * 16 + h * 4 + j;
                if (m0 + row < Ne) {
                    float aa = acc1[mi][nj][j], bb = acc3[mi][nj][j];
                    float hv = (aa / (1.f + expf(-aa))) * bb;
                    Ho[(size_t)(roff + m0 + row) * Nn + col] = f2bf(hv);
                }
            }
        }
    }
}

// ---------------- down-projection: Y = H @ W2 ----------------
// tile 128(M) x 128(N), BK=64; live = NB_DN * n_all (all items valid for all nb).
__global__ __launch_bounds__(256) void gemm2(
    const unsigned short* __restrict__ Hg,
    const unsigned short* __restrict__ Hs,
    const unsigned short* __restrict__ W2t,   // [8][D][H] bf16
    const unsigned short* __restrict__ sw2t,  // [D][HS]
    const int* __restrict__ offsets,
    float* __restrict__ Yg,
    float* __restrict__ out,
    const int* __restrict__ wl, const int* __restrict__ wl_n)
{
    int n_all = wl_n[0];
    int live = NB_DN * n_all;
    int L = xcd_live_map(blockIdx.x, live);
    if (L < 0 || L >= live) return;
    int nb = L / n_all, it = L % n_all;
    int pk = wl[it];
    int z = pk >> 16, m0 = pk & 0xffff;
    bool sh = (z == EEXP);
    int roff, Ne, Kd;
    const unsigned short *Ab, *Bb;
    float* Yo;
    if (sh) { roff = 0; Ne = T_TOK; Kd = HSDIM; Ab = Hs; Bb = sw2t; Yo = out; }
    else {
        roff = offsets[z]; Ne = offsets[z + 1] - roff; Kd = HDIM;
        Ab = Hg + (size_t)roff * HDIM;
        Bb = W2t + (size_t)z * DDIM * HDIM;
        Yo = Yg + (size_t)roff * DDIM;
    }
    int n0 = nb * 128;

    __shared__ __align__(16) unsigned short As[128 * 64];
    __shared__ __align__(16) unsigned short Bs[128 * 64];

    int tid = threadIdx.x, lane = tid & 63, wid = tid >> 6;
    int wr = wid >> 1, wc = wid & 1;
    int sc = ((lane & 7) ^ (lane >> 3)) * 8;

    const unsigned short* pA[4];
    const unsigned short* pB[4];
#pragma unroll
    for (int j = 0; j < 4; j++) {
        int lr = (wid * 4 + j) * 8 + (lane >> 3);
        int gr = m0 + lr; if (gr >= Ne) gr = Ne - 1;
        pA[j] = Ab + (size_t)gr * Kd + sc;
        pB[j] = Bb + (size_t)(n0 + lr) * Kd + sc;
    }

    const f32x4 fz = {0.f, 0.f, 0.f, 0.f};
    f32x4 acc[4][4];
#pragma unroll
    for (int mi = 0; mi < 4; mi++)
#pragma unroll
        for (int nj = 0; nj < 4; nj++) acc[mi][nj] = fz;

    int nks = Kd / BK;
#pragma unroll 1
    for (int ks = 0; ks < nks; ks++) {
        __syncthreads();
#pragma unroll
        for (int j = 0; j < 4; j++) gload16(pA[j], As + (wid * 4 + j) * 512);
#pragma unroll
        for (int j = 0; j < 4; j++) gload16(pB[j], Bs + (wid * 4 + j) * 512);
#pragma unroll
        for (int j = 0; j < 4; j++) { pA[j] += BK; pB[j] += BK; }
        __syncthreads();
        int r = lane & 15, h = lane >> 4, sw = (lane & 7) << 4;
#pragma unroll
        for (int kk = 0; kk < 2; kk++) {
            int cb = (kk * 64 + h * 16) ^ sw;
            bf16x8 a[4], b[4];
#pragma unroll
            for (int mi = 0; mi < 4; mi++)
                a[mi] = *(const bf16x8*)((const char*)As + (wr * 64 + mi * 16 + r) * 128 + cb);
#pragma unroll
            for (int nj = 0; nj < 4; nj++)
                b[nj] = *(const bf16x8*)((const char*)Bs + (wc * 64 + nj * 16 + r) * 128 + cb);
#pragma unroll
            for (int mi = 0; mi < 4; mi++)
#pragma unroll
                for (int nj = 0; nj < 4; nj++)
                    acc[mi][nj] = __builtin_amdgcn_mfma_f32_16x16x32_bf16(a[mi], b[nj], acc[mi][nj], 0, 0, 0);
        }
    }
    int r = lane & 15, h = lane >> 4;
#pragma unroll
    for (int mi = 0; mi < 4; mi++) {
#pragma unroll
        for (int nj = 0; nj < 4; nj++) {
            int col = n0 + wc * 64 + nj * 16 + r;
#pragma unroll
            for (int j = 0; j < 4; j++) {
                int row = wr * 64 + mi * 16 + h * 4 + j;
                if (m0 + row < Ne)
                    Yo[(size_t)(m0 + row) * DDIM + col] = acc[mi][nj][j];
            }
        }
    }
}

// ---------------- final combine ----------------
__global__ void combine_k(float* __restrict__ out, const float* __restrict__ Yg,
                          const int* __restrict__ rowof, const float* __restrict__ topw) {
    int idx = blockIdx.x * 256 + threadIdx.x;
    int t = idx >> 8;
    int dq = (idx & 255) << 2;
    int r0 = rowof[2 * t], r1 = rowof[2 * t + 1];
    float g0 = topw[2 * t], g1 = topw[2 * t + 1];
    float* op = out + (size_t)t * DDIM + dq;
    float4 o = *(float4*)op;
    float4 a = *(const float4*)(Yg + (size_t)r0 * DDIM + dq);
    float4 b = *(const float4*)(Yg + (size_t)r1 * DDIM + dq);
    o.x += g0 * a.x + g1 * b.x;
    o.y += g0 * a.y + g1 * b.y;
    o.z += g0 * a.z + g1 * b.z;
    o.w += g0 * a.w + g1 * b.w;
    *(float4*)op = o;
}

// ---------------- launch ----------------
extern "C" void kernel_launch(void* const* d_in, const int* in_sizes, int n_in,
                              void* d_out, int out_size, void* d_ws, size_t ws_size,
                              hipStream_t stream) {
    const float* x   = (const float*)d_in[0];
    const float* gw  = (const float*)d_in[1];
    const float* w1  = (const float*)d_in[2];
    const float* w3  = (const float*)d_in[3];
    const float* w2  = (const float*)d_in[4];
    const float* sw1 = (const float*)d_in[5];
    const float* sw3 = (const float*)d_in[6];
    const float* sw2 = (const float*)d_in[7];
    float* out = (float*)d_out;
    char* ws = (char*)d_ws;

    const size_t MB = 1048576;
    int*   counts     = (int*)(ws);
    int*   offsets    = (int*)(ws + 64);
    int*   cursors    = (int*)(ws + 128);
    int*   wl_n       = (int*)(ws + 192);     // [0]=total, [1]=routed
    int*   wl         = (int*)(ws + 256);
    int*   topi       = (int*)(ws + 512);
    float* topw       = (float*)(ws + 16896);
    int*   rows_token = (int*)(ws + 33280);
    int*   rowof      = (int*)(ws + 49664);
    unsigned short* Xb   = (unsigned short*)(ws + 1 * MB);    // 4 MB
    unsigned short* sw1t = (unsigned short*)(ws + 6 * MB);    // 3 MB
    unsigned short* sw3t = (unsigned short*)(ws + 9 * MB);    // 3 MB
    unsigned short* sw2t = (unsigned short*)(ws + 12 * MB);   // 3 MB
    unsigned short* Hg   = (unsigned short*)(ws + 16 * MB);   // 22 MB
    float*          Yg   = (float*)(ws + 40 * MB);            // 16 MB
    unsigned short* Hs   = (unsigned short*)(ws + 56 * MB);   // 6 MB
    unsigned short* W1t  = (unsigned short*)(ws + 64 * MB);   // 44 MB
    unsigned short* W3t  = (unsigned short*)(ws + 108 * MB);  // 44 MB (ends 152 MB)
    unsigned short* W2t  = W1t;  // aliased: converted after fused_up consumes W1t

    // routing
    init_k<<<1, 64, 0, stream>>>(counts, cursors);
    gate_k<<<T_TOK / 4, 256, 0, stream>>>(x, gw, topi, topw, counts);
    scan_k<<<1, 64, 0, stream>>>(counts, offsets, wl, wl_n);
    build_k<<<T_TOK / 256, 256, 0, stream>>>(topi, offsets, cursors, rows_token, rowof);

    // pre-pass: xcast + W1/W3/shared transposes (W2 deferred for L3 warmth)
    prep_k<<<PREP_GRID, 256, 0, stream>>>(x, w1, w3, sw1, sw3, sw2,
                                          Xb, W1t, W3t, sw1t, sw3t, sw2t);

    // up-projection (reads W1t/W3t L3-warm from prep)
    fused_up<<<GRID_UP, 256, 0, stream>>>(
        Xb, rows_token, offsets, W1t, W3t, sw1t, sw3t, Hg, Hs, wl, wl_n);

    // W2 transpose into aliased region (after fused_up drained W1t);
    // gemm2 then reads W2t L3-warm.
    tcast_k<<<dim3(DDIM / 64, HDIM / 128, EEXP), 256, 0, stream>>>(w2, W2t, HDIM, DDIM);

    // down-projection (routed -> Yg, shared -> out direct)
    gemm2<<<GRID_DN, 256, 0, stream>>>(
        Hg, Hs, W2t, sw2t, offsets, Yg, out, wl, wl_n);

    // out = shared + g0*y0 + g1*y1
    combine_k<<<(T_TOK * DDIM / 4) / 256, 256, 0, stream>>>(out, Yg, rowof, topw);
}

// Round 10
// 290.703 us; speedup vs baseline: 1.0826x; 1.0216x over previous
//
#include <hip/hip_runtime.h>
#include <hip/hip_bf16.h>

// Problem constants
#define T_TOK 2048      // B*S
#define DDIM  1024
#define EEXP  8
#define KTOP  2
#define HDIM  2816
#define HSDIM 1536
#define BK    64
#define MT    128       // GEMM m-tile
#define NB_UP 22        // HDIM/128
#define NB_SH 12        // HSDIM/128
#define NB_DN 8         // DDIM/128
#define GRID_UP 1072    // max live: 12*56 + 10*40
#define GRID_DN 448     // 8*56

typedef float f32x4 __attribute__((ext_vector_type(4)));
typedef short bf16x8 __attribute__((ext_vector_type(8)));

__device__ __forceinline__ unsigned short f2bf(float f) {
    __hip_bfloat16 h = __float2bfloat16(f);
    return __builtin_bit_cast(unsigned short, h);
}

// async global->LDS, 16B per lane; LDS dest = wave-uniform base + lane*16
__device__ __forceinline__ void gload16(const void* g, void* l) {
    __builtin_amdgcn_global_load_lds(
        (const __attribute__((address_space(1))) unsigned int*)g,
        (__attribute__((address_space(3))) unsigned int*)l, 16, 0, 0);
}

// Bijective chunked XCD remap over a RUNTIME live count (m204 general form).
__device__ __forceinline__ int xcd_live_map(int i, int n) {
    int q = n >> 3, r = n & 7;
    int xcd = i & 7, loc = i >> 3;
    int cap = q + (xcd < r ? 1 : 0);
    if (loc >= cap) return -1;
    return (xcd < r ? xcd * (q + 1) : r * (q + 1) + (xcd - r) * q) + loc;
}

// ---------------- small routing kernels ----------------

__global__ void init_k(int* counts, int* cursors) {
    if (threadIdx.x < EEXP) { counts[threadIdx.x] = 0; cursors[threadIdx.x] = 0; }
}

__global__ void gate_k(const float* __restrict__ X, const float* __restrict__ GW,
                       int* __restrict__ topi, float* __restrict__ topw,
                       int* __restrict__ counts) {
    int lane = threadIdx.x & 63;
    int t = blockIdx.x * 4 + (threadIdx.x >> 6);
    int e  = lane >> 3;
    int c8 = lane & 7;
    const float* xr = X + (size_t)t * DDIM;
    const float* gr = GW + (size_t)e * DDIM;
    float acc = 0.f;
#pragma unroll 8
    for (int j = 0; j < 32; j++) {
        int d = (c8 + 8 * j) * 4;
        float4 xv = *(const float4*)(xr + d);
        float4 gv = *(const float4*)(gr + d);
        acc += xv.x * gv.x + xv.y * gv.y + xv.z * gv.z + xv.w * gv.w;
    }
    acc += __shfl_xor(acc, 1);
    acc += __shfl_xor(acc, 2);
    acc += __shfl_xor(acc, 4);
    float p[8];
#pragma unroll
    for (int q = 0; q < 8; q++) p[q] = __shfl(acc, q * 8);
    float mx = p[0];
#pragma unroll
    for (int q = 1; q < 8; q++) mx = fmaxf(mx, p[q]);
    float s = 0.f;
#pragma unroll
    for (int q = 0; q < 8; q++) { p[q] = expf(p[q] - mx); s += p[q]; }
    float inv = 1.f / s;
#pragma unroll
    for (int q = 0; q < 8; q++) p[q] *= inv;
    float v1 = -1.f; int i1 = 0;
#pragma unroll
    for (int q = 0; q < 8; q++) { if (p[q] > v1) { v1 = p[q]; i1 = q; } }
    float v2 = -1.f; int i2 = 0;
#pragma unroll
    for (int q = 0; q < 8; q++) { if (q != i1 && p[q] > v2) { v2 = p[q]; i2 = q; } }
    if (lane == 0) {
        topi[2 * t] = i1; topi[2 * t + 1] = i2;
        topw[2 * t] = v1; topw[2 * t + 1] = v2;
        atomicAdd(&counts[i1], 1);
        atomicAdd(&counts[i2], 1);
    }
}

// prefix-sum + device-built tile worklist: (e<<16)|m0 ; routed tiles FIRST,
// then shared-expert (e=8) tiles. wl_n[0]=total items, wl_n[1]=routed items.
__global__ void scan_k(const int* __restrict__ counts, int* __restrict__ offsets,
                       int* __restrict__ wl, int* __restrict__ wl_n) {
    if (threadIdx.x == 0) {
        int s = 0;
        for (int e = 0; e < EEXP; e++) { offsets[e] = s; s += counts[e]; }
        offsets[EEXP] = s;
        int n = 0;
        for (int e = 0; e < EEXP; e++) {
            int Ne = counts[e];
            for (int m0 = 0; m0 < Ne; m0 += MT) wl[n++] = (e << 16) | m0;
        }
        wl_n[1] = n;                       // routed count
        for (int m0 = 0; m0 < T_TOK; m0 += MT) wl[n++] = (EEXP << 16) | m0;
        wl_n[0] = n;                       // total (<= 56)
    }
}

__global__ void build_k(const int* __restrict__ topi, const int* __restrict__ offsets,
                        int* __restrict__ cursors, int* __restrict__ rows_token,
                        int* __restrict__ rowof) {
    int t = blockIdx.x * 256 + threadIdx.x;
    if (t >= T_TOK) return;
    for (int k = 0; k < KTOP; k++) {
        int e = topi[2 * t + k];
        int pos = atomicAdd(&cursors[e], 1);
        int r = offsets[e] + pos;
        rows_token[r] = t;
        rowof[2 * t + k] = r;
    }
}

// ---------------- pre-pass: cast & transpose into CHUNKED layout ----------------
// Chunked transposed-weight layout (GEMM gathers per-lane, so layout is free):
//   Wt_c[(kb*Nn + n)*32 + c4*8 + e] = bf16(W[kb*32 + c4*8 + e][n])
//   (u16 units; kb = k/32, c4 = (k/8)&3, e = k&7 -> each 16B chunk = 8 k-consec)
// Prep tile = 32(k) x 256(n): loads are 1KB-contiguous rows (one wave-instr each),
// stores are 1KB-contiguous (lane -> (n,c4) interleave). R9 post-mortem: 256B
// segments at 11KB stride were DRAM-efficiency-bound at 2.35 TB/s.
__device__ __forceinline__ void tcast_tile(const float* __restrict__ S,
                                           unsigned short* __restrict__ Dc,
                                           int Kd, int Nn, int k0, int n0,
                                           float* __restrict__ ld /*[32*256]*/) {
    int tid = threadIdx.x, lane = tid & 63, w = tid >> 6;
#pragma unroll
    for (int j = 0; j < 8; j++) {
        int r = j * 4 + w;                         // k-row 0..31
        gload16(S + (size_t)(k0 + r) * Nn + n0 + lane * 4, ld + r * 256);
    }
    __syncthreads();
    int c4 = tid & 3;
    int nh = tid >> 2;                             // 0..63
    size_t kb = (size_t)(k0 >> 5);
#pragma unroll
    for (int s = 0; s < 4; s++) {
        int nloc = s * 64 + nh;
        unsigned short o[8];
#pragma unroll
        for (int jj = 0; jj < 8; jj++)
            o[jj] = f2bf(ld[(c4 * 8 + jj) * 256 + nloc]);
        *(uint4*)(Dc + (kb * Nn + n0 + nloc) * 32 + c4 * 8) = *(const uint4*)o;
    }
}

// job table (W2 deliberately NOT here: its transpose runs AFTER fused_up so
// W1t/W3t stay L3-warm for fused_up and W2t stays warm for gemm2 — R8 lesson):
//  [0,1024)       xcast: X f32 -> Xb bf16
//  [1024,3840)    w1  -> W1t   (z, 32kb x 11nb = 352)
//  [3840,6656)    w3  -> W3t
//  [6656,6848)    sw1 -> sw1t  (32kb x 6nb = 192)
//  [6848,7040)    sw3 -> sw3t
//  [7040,7232)    sw2 -> sw2t  (48kb x 4nb = 192)
#define PREP_GRID 7232

__global__ __launch_bounds__(256) void prep_k(
    const float* __restrict__ x,
    const float* __restrict__ w1, const float* __restrict__ w3,
    const float* __restrict__ sw1, const float* __restrict__ sw3,
    const float* __restrict__ sw2,
    unsigned short* __restrict__ Xb,
    unsigned short* __restrict__ W1t, unsigned short* __restrict__ W3t,
    unsigned short* __restrict__ sw1t, unsigned short* __restrict__ sw3t,
    unsigned short* __restrict__ sw2t)
{
    __shared__ __align__(16) float ld[32 * 256];
    int b = blockIdx.x;
    if (b < 1024) {
        int i = b * 2048 + threadIdx.x * 8;
        float4 a = *(const float4*)(x + i);
        float4 c = *(const float4*)(x + i + 4);
        unsigned short o[8] = { f2bf(a.x), f2bf(a.y), f2bf(a.z), f2bf(a.w),
                                f2bf(c.x), f2bf(c.y), f2bf(c.z), f2bf(c.w) };
        *(uint4*)(Xb + i) = *(const uint4*)o;
        return;
    }
    const float* S; unsigned short* D; int Kd, Nn, k0, n0;
    if (b < 3840) {
        int idx = b - 1024, z = idx / 352, r = idx % 352;
        Kd = DDIM; Nn = HDIM;
        S = w1 + (size_t)z * DDIM * HDIM; D = W1t + (size_t)z * DDIM * HDIM;
        k0 = (r / 11) * 32; n0 = (r % 11) * 256;
    } else if (b < 6656) {
        int idx = b - 3840, z = idx / 352, r = idx % 352;
        Kd = DDIM; Nn = HDIM;
        S = w3 + (size_t)z * DDIM * HDIM; D = W3t + (size_t)z * DDIM * HDIM;
        k0 = (r / 11) * 32; n0 = (r % 11) * 256;
    } else if (b < 6848) {
        int idx = b - 6656;
        Kd = DDIM; Nn = HSDIM; S = sw1; D = sw1t;
        k0 = (idx / 6) * 32; n0 = (idx % 6) * 256;
    } else if (b < 7040) {
        int idx = b - 6848;
        Kd = DDIM; Nn = HSDIM; S = sw3; D = sw3t;
        k0 = (idx / 6) * 32; n0 = (idx % 6) * 256;
    } else {
        int idx = b - 7040;
        Kd = HSDIM; Nn = DDIM; S = sw2; D = sw2t;
        k0 = (idx / 4) * 32; n0 = (idx % 4) * 256;
    }
    tcast_tile(S, D, Kd, Nn, k0, n0, ld);
    (void)Kd;
}

// W [z][K][N] f32 -> chunked Wt (W2 path, aliased region, runs after fused_up)
__global__ __launch_bounds__(256) void tcast_k(const float* __restrict__ S,
                                               unsigned short* __restrict__ Dm,
                                               int Kd, int Nn) {
    __shared__ __align__(16) float ld[32 * 256];
    size_t zoff = (size_t)blockIdx.z * Kd * Nn;
    tcast_tile(S + zoff, Dm + zoff, Kd, Nn, blockIdx.y * 32, blockIdx.x * 256, ld);
}

// ---------------- fused up-projection: H = silu(X@W1) * (X@W3) ----------------
// tile 128(M) x 128(N), BK=64, 4 waves 2x2, per-wave 64x64 dual-accumulated.
// B gathered from chunked layout: per-lane addr advances by 64*Nn u16 per K-step.
__global__ __launch_bounds__(256, 2) void fused_up(
    const unsigned short* __restrict__ Xb,
    const int* __restrict__ rows_token,
    const int* __restrict__ offsets,
    const unsigned short* __restrict__ W1t,   // [8] chunked (Nn=HDIM)
    const unsigned short* __restrict__ W3t,
    const unsigned short* __restrict__ sw1t,  // chunked (Nn=HSDIM)
    const unsigned short* __restrict__ sw3t,
    unsigned short* __restrict__ Hg,          // [4096][H]
    unsigned short* __restrict__ Hs,          // [2048][HS]
    const int* __restrict__ wl, const int* __restrict__ wl_n)
{
    int n_all = wl_n[0], n_r = wl_n[1];
    int live = NB_SH * n_all + (NB_UP - NB_SH) * n_r;
    int L = xcd_live_map(blockIdx.x, live);
    if (L < 0 || L >= live) return;
    int nb, it;
    if (L < NB_SH * n_all) { nb = L / n_all; it = L % n_all; }
    else { int L2 = L - NB_SH * n_all; nb = NB_SH + L2 / n_r; it = L2 % n_r; }
    int pk = wl[it];
    int z = pk >> 16, m0 = pk & 0xffff;
    bool sh = (z == EEXP);
    int roff, Ne, Nn;
    const unsigned short *w1, *w3;
    unsigned short* Ho;
    if (sh) { roff = 0; Ne = T_TOK; Nn = HSDIM; w1 = sw1t; w3 = sw3t; Ho = Hs; }
    else {
        roff = offsets[z]; Ne = offsets[z + 1] - roff; Nn = HDIM;
        w1 = W1t + (size_t)z * HDIM * DDIM;
        w3 = W3t + (size_t)z * HDIM * DDIM;
        Ho = Hg;
    }
    int n0 = nb * 128;
    if (n0 >= Nn) return;

    __shared__ __align__(16) unsigned short As [128 * 64];
    __shared__ __align__(16) unsigned short B1s[128 * 64];
    __shared__ __align__(16) unsigned short B3s[128 * 64];

    int tid = threadIdx.x, lane = tid & 63, wid = tid >> 6;
    int wr = wid >> 1, wc = wid & 1;          // per-wave 64 rows x 64 cols
    int cl = (lane & 7) ^ (lane >> 3);        // swizzled chunk index 0..7

    size_t bstep = (size_t)64 * Nn;           // chunked-layout K-step stride (u16)
    const unsigned short* pA[4];
    const unsigned short *pB1[4], *pB3[4];
#pragma unroll
    for (int j = 0; j < 4; j++) {
        int lr = (wid * 4 + j) * 8 + (lane >> 3);
        int gr = m0 + lr; if (gr >= Ne) gr = Ne - 1;
        int tok = sh ? gr : rows_token[roff + gr];
        pA[j]  = Xb + (size_t)tok * DDIM + cl * 8;
        size_t boff = ((size_t)(cl >> 2) * Nn + n0 + lr) * 32 + (cl & 3) * 8;
        pB1[j] = w1 + boff;
        pB3[j] = w3 + boff;
    }

    const f32x4 fz = {0.f, 0.f, 0.f, 0.f};
    f32x4 acc1[4][4], acc3[4][4];
#pragma unroll
    for (int mi = 0; mi < 4; mi++)
#pragma unroll
        for (int nj = 0; nj < 4; nj++) { acc1[mi][nj] = fz; acc3[mi][nj] = fz; }

#pragma unroll 1
    for (int ks = 0; ks < DDIM / BK; ks++) {
        __syncthreads();
#pragma unroll
        for (int j = 0; j < 4; j++) gload16(pA[j],  As  + (wid * 4 + j) * 512);
#pragma unroll
        for (int j = 0; j < 4; j++) gload16(pB1[j], B1s + (wid * 4 + j) * 512);
#pragma unroll
        for (int j = 0; j < 4; j++) gload16(pB3[j], B3s + (wid * 4 + j) * 512);
#pragma unroll
        for (int j = 0; j < 4; j++) { pA[j] += BK; pB1[j] += bstep; pB3[j] += bstep; }
        __syncthreads();
        int r = lane & 15, h = lane >> 4, sw = (lane & 7) << 4;
#pragma unroll
        for (int kk = 0; kk < 2; kk++) {
            int cb = (kk * 64 + h * 16) ^ sw;
            bf16x8 a[4], b1[4], b3[4];
#pragma unroll
            for (int mi = 0; mi < 4; mi++)
                a[mi] = *(const bf16x8*)((const char*)As + (wr * 64 + mi * 16 + r) * 128 + cb);
#pragma unroll
            for (int nj = 0; nj < 4; nj++) {
                b1[nj] = *(const bf16x8*)((const char*)B1s + (wc * 64 + nj * 16 + r) * 128 + cb);
                b3[nj] = *(const bf16x8*)((const char*)B3s + (wc * 64 + nj * 16 + r) * 128 + cb);
            }
#pragma unroll
            for (int mi = 0; mi < 4; mi++)
#pragma unroll
                for (int nj = 0; nj < 4; nj++) {
                    acc1[mi][nj] = __builtin_amdgcn_mfma_f32_16x16x32_bf16(a[mi], b1[nj], acc1[mi][nj], 0, 0, 0);
                    acc3[mi][nj] = __builtin_amdgcn_mfma_f32_16x16x32_bf16(a[mi], b3[nj], acc3[mi][nj], 0, 0, 0);
                }
        }
    }
    int r = lane & 15, h = lane >> 4;
#pragma unroll
    for (int mi = 0; mi < 4; mi++) {
#pragma unroll
        for (int nj = 0; nj < 4; nj++) {
            int col = n0 + wc * 64 + nj * 16 + r;
#pragma unroll
            for (int j = 0; j < 4; j++) {
                int row = wr * 64 + mi * 16 + h * 4 + j;
                if (m0 + row < Ne) {
                    float aa = acc1[mi][nj][j], bb = acc3[mi][nj][j];
                    float hv = (aa / (1.f + expf(-aa))) * bb;
                    Ho[(size_t)(roff + m0 + row) * Nn + col] = f2bf(hv);
                }
            }
        }
    }
}

// ---------------- down-projection: Y = H @ W2 ----------------
// tile 128(M) x 128(N), BK=64; B gathered from chunked layout (Nn = DDIM).
__global__ __launch_bounds__(256) void gemm2(
    const unsigned short* __restrict__ Hg,
    const unsigned short* __restrict__ Hs,
    const unsigned short* __restrict__ W2t,   // [8] chunked (Nn=DDIM)
    const unsigned short* __restrict__ sw2t,  // chunked (Nn=DDIM)
    const int* __restrict__ offsets,
    float* __restrict__ Yg,
    float* __restrict__ out,
    const int* __restrict__ wl, const int* __restrict__ wl_n)
{
    int n_all = wl_n[0];
    int live = NB_DN * n_all;
    int L = xcd_live_map(blockIdx.x, live);
    if (L < 0 || L >= live) return;
    int nb = L / n_all, it = L % n_all;
    int pk = wl[it];
    int z = pk >> 16, m0 = pk & 0xffff;
    bool sh = (z == EEXP);
    int roff, Ne, Kd;
    const unsigned short *Ab, *Bb;
    float* Yo;
    if (sh) { roff = 0; Ne = T_TOK; Kd = HSDIM; Ab = Hs; Bb = sw2t; Yo = out; }
    else {
        roff = offsets[z]; Ne = offsets[z + 1] - roff; Kd = HDIM;
        Ab = Hg + (size_t)roff * HDIM;
        Bb = W2t + (size_t)z * DDIM * HDIM;
        Yo = Yg + (size_t)roff * DDIM;
    }
    int n0 = nb * 128;

    __shared__ __align__(16) unsigned short As[128 * 64];
    __shared__ __align__(16) unsigned short Bs[128 * 64];

    int tid = threadIdx.x, lane = tid & 63, wid = tid >> 6;
    int wr = wid >> 1, wc = wid & 1;
    int cl = (lane & 7) ^ (lane >> 3);

    const size_t bstep = (size_t)64 * DDIM;   // chunked stride (u16), Nn = DDIM
    const unsigned short* pA[4];
    const unsigned short* pB[4];
#pragma unroll
    for (int j = 0; j < 4; j++) {
        int lr = (wid * 4 + j) * 8 + (lane >> 3);
        int gr = m0 + lr; if (gr >= Ne) gr = Ne - 1;
        pA[j] = Ab + (size_t)gr * Kd + cl * 8;
        pB[j] = Bb + ((size_t)(cl >> 2) * DDIM + n0 + lr) * 32 + (cl & 3) * 8;
    }

    const f32x4 fz = {0.f, 0.f, 0.f, 0.f};
    f32x4 acc[4][4];
#pragma unroll
    for (int mi = 0; mi < 4; mi++)
#pragma unroll
        for (int nj = 0; nj < 4; nj++) acc[mi][nj] = fz;

    int nks = Kd / BK;
#pragma unroll 1
    for (int ks = 0; ks < nks; ks++) {
        __syncthreads();
#pragma unroll
        for (int j = 0; j < 4; j++) gload16(pA[j], As + (wid * 4 + j) * 512);
#pragma unroll
        for (int j = 0; j < 4; j++) gload16(pB[j], Bs + (wid * 4 + j) * 512);
#pragma unroll
        for (int j = 0; j < 4; j++) { pA[j] += BK; pB[j] += bstep; }
        __syncthreads();
        int r = lane & 15, h = lane >> 4, sw = (lane & 7) << 4;
#pragma unroll
        for (int kk = 0; kk < 2; kk++) {
            int cb = (kk * 64 + h * 16) ^ sw;
            bf16x8 a[4], b[4];
#pragma unroll
            for (int mi = 0; mi < 4; mi++)
                a[mi] = *(const bf16x8*)((const char*)As + (wr * 64 + mi * 16 + r) * 128 + cb);
#pragma unroll
            for (int nj = 0; nj < 4; nj++)
                b[nj] = *(const bf16x8*)((const char*)Bs + (wc * 64 + nj * 16 + r) * 128 + cb);
#pragma unroll
            for (int mi = 0; mi < 4; mi++)
#pragma unroll
                for (int nj = 0; nj < 4; nj++)
                    acc[mi][nj] = __builtin_amdgcn_mfma_f32_16x16x32_bf16(a[mi], b[nj], acc[mi][nj], 0, 0, 0);
        }
    }
    int r = lane & 15, h = lane >> 4;
#pragma unroll
    for (int mi = 0; mi < 4; mi++) {
#pragma unroll
        for (int nj = 0; nj < 4; nj++) {
            int col = n0 + wc * 64 + nj * 16 + r;
#pragma unroll
            for (int j = 0; j < 4; j++) {
                int row = wr * 64 + mi * 16 + h * 4 + j;
                if (m0 + row < Ne)
                    Yo[(size_t)(m0 + row) * DDIM + col] = acc[mi][nj][j];
            }
        }
    }
}

// ---------------- final combine ----------------
__global__ void combine_k(float* __restrict__ out, const float* __restrict__ Yg,
                          const int* __restrict__ rowof, const float* __restrict__ topw) {
    int idx = blockIdx.x * 256 + threadIdx.x;
    int t = idx >> 8;
    int dq = (idx & 255) << 2;
    int r0 = rowof[2 * t], r1 = rowof[2 * t + 1];
    float g0 = topw[2 * t], g1 = topw[2 * t + 1];
    float* op = out + (size_t)t * DDIM + dq;
    float4 o = *(float4*)op;
    float4 a = *(const float4*)(Yg + (size_t)r0 * DDIM + dq);
    float4 b = *(const float4*)(Yg + (size_t)r1 * DDIM + dq);
    o.x += g0 * a.x + g1 * b.x;
    o.y += g0 * a.y + g1 * b.y;
    o.z += g0 * a.z + g1 * b.z;
    o.w += g0 * a.w + g1 * b.w;
    *(float4*)op = o;
}

// ---------------- launch ----------------
extern "C" void kernel_launch(void* const* d_in, const int* in_sizes, int n_in,
                              void* d_out, int out_size, void* d_ws, size_t ws_size,
                              hipStream_t stream) {
    const float* x   = (const float*)d_in[0];
    const float* gw  = (const float*)d_in[1];
    const float* w1  = (const float*)d_in[2];
    const float* w3  = (const float*)d_in[3];
    const float* w2  = (const float*)d_in[4];
    const float* sw1 = (const float*)d_in[5];
    const float* sw3 = (const float*)d_in[6];
    const float* sw2 = (const float*)d_in[7];
    float* out = (float*)d_out;
    char* ws = (char*)d_ws;

    const size_t MB = 1048576;
    int*   counts     = (int*)(ws);
    int*   offsets    = (int*)(ws + 64);
    int*   cursors    = (int*)(ws + 128);
    int*   wl_n       = (int*)(ws + 192);     // [0]=total, [1]=routed
    int*   wl         = (int*)(ws + 256);
    int*   topi       = (int*)(ws + 512);
    float* topw       = (float*)(ws + 16896);
    int*   rows_token = (int*)(ws + 33280);
    int*   rowof      = (int*)(ws + 49664);
    unsigned short* Xb   = (unsigned short*)(ws + 1 * MB);    // 4 MB
    unsigned short* sw1t = (unsigned short*)(ws + 6 * MB);    // 3 MB
    unsigned short* sw3t = (unsigned short*)(ws + 9 * MB);    // 3 MB
    unsigned short* sw2t = (unsigned short*)(ws + 12 * MB);   // 3 MB
    unsigned short* Hg   = (unsigned short*)(ws + 16 * MB);   // 22 MB
    float*          Yg   = (float*)(ws + 40 * MB);            // 16 MB
    unsigned short* Hs   = (unsigned short*)(ws + 56 * MB);   // 6 MB
    unsigned short* W1t  = (unsigned short*)(ws + 64 * MB);   // 44 MB
    unsigned short* W3t  = (unsigned short*)(ws + 108 * MB);  // 44 MB (ends 152 MB)
    unsigned short* W2t  = W1t;  // aliased: converted after fused_up consumes W1t

    // routing
    init_k<<<1, 64, 0, stream>>>(counts, cursors);
    gate_k<<<T_TOK / 4, 256, 0, stream>>>(x, gw, topi, topw, counts);
    scan_k<<<1, 64, 0, stream>>>(counts, offsets, wl, wl_n);
    build_k<<<T_TOK / 256, 256, 0, stream>>>(topi, offsets, cursors, rows_token, rowof);

    // pre-pass: xcast + W1/W3/shared transposes (W2 deferred for L3 warmth)
    prep_k<<<PREP_GRID, 256, 0, stream>>>(x, w1, w3, sw1, sw3, sw2,
                                          Xb, W1t, W3t, sw1t, sw3t, sw2t);

    // up-projection (reads W1t/W3t L3-warm from prep)
    fused_up<<<GRID_UP, 256, 0, stream>>>(
        Xb, rows_token, offsets, W1t, W3t, sw1t, sw3t, Hg, Hs, wl, wl_n);

    // W2 transpose into aliased region (after fused_up drained W1t);
    // gemm2 then reads W2t L3-warm.  grid: 4 nb x 88 kb x 8 experts
    tcast_k<<<dim3(DDIM / 256, HDIM / 32, EEXP), 256, 0, stream>>>(w2, W2t, HDIM, DDIM);

    // down-projection (routed -> Yg, shared -> out direct)
    gemm2<<<GRID_DN, 256, 0, stream>>>(
        Hg, Hs, W2t, sw2t, offsets, Yg, out, wl, wl_n);

    // out = shared + g0*y0 + g1*y1
    combine_k<<<(T_TOK * DDIM / 4) / 256, 256, 0, stream>>>(out, Yg, rowof, topw);
}